// Round 6
// baseline (455.202 us; speedup 1.0000x reference)
//
#include <hip/hip_runtime.h>
#include <hip/hip_bf16.h>

#define B_N 128
#define T_N 2048
#define H_N 512

typedef __attribute__((ext_vector_type(8))) short bf16x8;   // 8 bf16 = 4 VGPRs
typedef __attribute__((ext_vector_type(4))) float f32x4;    // MFMA acc

union U4 { unsigned int i[4]; bf16x8 v; };

// RNE f32 -> bf16 (low 16 bits)
__device__ __forceinline__ unsigned int f2bf(float f) {
    unsigned int u = __float_as_uint(f);
    u += 0x7fffu + ((u >> 16) & 1u);
    return u >> 16;
}

// packed f32x2 -> bf16x2 (RNE), single VALU inst
__device__ __forceinline__ unsigned int cvtpk(float lo, float hi) {
    unsigned int r;
    asm("v_cvt_pk_bf16_f32 %0, %1, %2" : "=v"(r) : "v"(lo), "v"(hi));
    return r;
}

// x >= 0 always here (relu+relu)
__device__ __forceinline__ float tanh_fast(float x) {
    float e = __expf(2.f * x);
    float r = __builtin_amdgcn_rcpf(e + 1.f);
    return 1.f - 2.f * r;
}

#define FENCE asm volatile("" ::: "memory")
#define SBAR  do { FENCE; __builtin_amdgcn_s_barrier(); FENCE; } while (0)
#define VMCNT(n) asm volatile("s_waitcnt vmcnt(" #n ")" ::: "memory")
#define LGKM0    asm volatile("s_waitcnt lgkmcnt(0)" ::: "memory")
#define SCHED0   __builtin_amdgcn_sched_barrier(0)

// ---------------------------------------------------------------------------
// K2: w2 (512x512 f32) -> bf16, pre-swizzled within each 1024B row:
// dst_byte(g,k) = g*1024 + ((k*2) ^ ((g&7)<<4)). Staged LINEARLY into LDS;
// fragment read applies byte^((row&7)<<4), cancelling (even swizzle count).
// ---------------------------------------------------------------------------
__global__ void k_w2prep(const float* __restrict__ w2, unsigned short* __restrict__ w2sw) {
    int c = blockIdx.x * 256 + threadIdx.x;      // 32768 chunks of 8 elems
    int g = c >> 6, kc = c & 63;
    const float4* s = reinterpret_cast<const float4*>(w2 + (size_t)g * H_N + kc * 8);
    float4 f0 = s[0], f1 = s[1];
    uint4 p;
    p.x = f2bf(f0.x) | (f2bf(f0.y) << 16);
    p.y = f2bf(f0.z) | (f2bf(f0.w) << 16);
    p.z = f2bf(f1.x) | (f2bf(f1.y) << 16);
    p.w = f2bf(f1.z) | (f2bf(f1.w) << 16);
    *reinterpret_cast<uint4*>(reinterpret_cast<char*>(w2sw) + (size_t)g * 1024 +
                              (((kc * 16) ^ ((g & 7) << 4)))) = p;
}

// ---------------------------------------------------------------------------
// K1: q_h[b][g] = relu(query[b]·w1[g])   (f32, tiny; w1 L2-resident)
// ---------------------------------------------------------------------------
__global__ void k_qh(const float* __restrict__ query, const float* __restrict__ w1,
                     float* __restrict__ qh) {
    int b = blockIdx.x;
    int g = threadIdx.x;                          // 512 threads
    __shared__ float q[H_N];
    q[g] = query[(size_t)b * H_N + g];
    __syncthreads();
    const float4* w = reinterpret_cast<const float4*>(w1 + (size_t)g * H_N);
    float acc = 0.f;
#pragma unroll 4
    for (int i = 0; i < H_N / 4; ++i) {
        float4 wv = w[i];
        acc += q[4*i] * wv.x + q[4*i+1] * wv.y + q[4*i+2] * wv.z + q[4*i+3] * wv.w;
    }
    qh[(size_t)b * H_N + g] = fmaxf(acc, 0.f);
}

// ---------------------------------------------------------------------------
// K3 (fused): per block of 128 t-rows:
//   s_t = sum_g w_out[g]*tanh(qh[b][g] + relu(key[b][t]·w2[g]))  -> w_t=exp(s_t)
//   psum[b][c] = sum_t w_t ;  partial[b][c][h] = sum_t w_t*key[t][h]
// GEMM: BM=128, BN=512 (SINGLE sweep -> key fetched once), BK=64, 8 steps.
// 8 waves 2wr x 4wc, wave tile 64t x 128g (4m x 8n frags of 16x16x32).
//   A (key, HBM): reg-staged f32 loads 2 steps ahead -> cvt_pk -> ds_write
//     into bf16 tile, 128B rows, XOR swizzle (r2's proven 0-conflict layout).
//     Single-buffered (write happens after compute(s) barrier).
//   B (w2sw, L2): 512x64 bf16 dbuf via global_load_lds, linear copy of
//     pre-swizzled rows.
// Counted vmcnt: steady vmcnt(12)->A regs, vmcnt(4)->B landed (A(s+2) stays
// in flight); never 0 mid-loop. LDS 144KB -> 1 block/CU. HBM-bound by design.
// ---------------------------------------------------------------------------
__global__ __launch_bounds__(512, 2) void k_scores(
    const float* __restrict__ key, const unsigned short* __restrict__ w2sw,
    const float* __restrict__ qh, const float* __restrict__ w_out,
    float* __restrict__ partial, float* __restrict__ psum)
{
    const int b    = blockIdx.y;
    const int chnk = blockIdx.x;
    const int t0   = chnk * 128;
    const int tid  = threadIdx.x;
    const int wid  = tid >> 6;
    const int lane = tid & 63;
    const int lrow = lane & 15;        // fragment row/col
    const int lq   = lane >> 4;        // 0..3 k-group
    const int wr   = wid >> 2;         // 0..1 t half (64 rows)
    const int wc   = wid & 3;          // 0..3 g quarter (128 g)
    const int swzR = (lrow & 7) << 4;  // byte XOR for fragment reads

    // [0,64K): B buf0; [64K,128K): B buf1; [128K,144K): A bf16 tile
    __shared__ __align__(16) char smem[147456];
    char* Abuf = smem + 131072;
    float* sscore = reinterpret_cast<float*>(smem);          // post-loop alias
    float* wlds   = reinterpret_cast<float*>(smem + 2048);   // post-loop alias

    const char* keybB = reinterpret_cast<const char*>(key + ((size_t)b * T_N + t0) * H_N);
    const char* w2sb  = reinterpret_cast<const char*>(w2sw);

    // ---- per-thread epilogue constants (issued first; drain early) ----
    float wo_r[8], qh_r[8];
#pragma unroll
    for (int n = 0; n < 8; ++n) {
        int g = wc * 128 + n * 16 + lrow;
        wo_r[n] = w_out[g];
        qh_r[n] = qh[(size_t)b * H_N + g];
    }

    // A staging geometry: thread -> (row = tid>>2, 16 contiguous k at (tid&3)*16)
    const int arow = tid >> 2;
    const int acol = tid & 3;
    const char* asrc = keybB + (size_t)arow * 2048 + acol * 64;   // 64B = 16 f32
    const int awb0 = arow * 128 + ((acol * 32)      ^ ((arow & 7) << 4));
    const int awb1 = arow * 128 + ((acol * 32 + 16) ^ ((arow & 7) << 4));

    float4 rA0[4], rA1[4];   // two pipeline reg sets: A(u) lives in set (u&1)

#define LOAD_A(u, R) do {                                        \
        const char* p_ = asrc + ((u) << 8);                      \
        R[0] = *reinterpret_cast<const float4*>(p_);             \
        R[1] = *reinterpret_cast<const float4*>(p_ + 16);        \
        R[2] = *reinterpret_cast<const float4*>(p_ + 32);        \
        R[3] = *reinterpret_cast<const float4*>(p_ + 48);        \
    } while (0)

#define WRITE_A(R) do {                                          \
        U4 u0_, u1_;                                             \
        u0_.i[0] = cvtpk(R[0].x, R[0].y);                        \
        u0_.i[1] = cvtpk(R[0].z, R[0].w);                        \
        u0_.i[2] = cvtpk(R[1].x, R[1].y);                        \
        u0_.i[3] = cvtpk(R[1].z, R[1].w);                        \
        u1_.i[0] = cvtpk(R[2].x, R[2].y);                        \
        u1_.i[1] = cvtpk(R[2].z, R[2].w);                        \
        u1_.i[2] = cvtpk(R[3].x, R[3].y);                        \
        u1_.i[3] = cvtpk(R[3].z, R[3].w);                        \
        *reinterpret_cast<bf16x8*>(Abuf + awb0) = u0_.v;         \
        *reinterpret_cast<bf16x8*>(Abuf + awb1) = u1_.v;         \
    } while (0)

#define STAGE_B(u) do {                                          \
        char* dstB_ = smem + (((u) & 1) << 16);                  \
        const char* srcB_ = w2sb + ((u) << 7);                   \
        _Pragma("unroll")                                        \
        for (int i_ = 0; i_ < 8; ++i_) {                         \
            int c0_ = i_ * 512 + wid * 64;                       \
            int c_  = c0_ + lane;                                \
            int row_ = c_ >> 3, slot_ = c_ & 7;                  \
            __builtin_amdgcn_global_load_lds(                    \
                (const __attribute__((address_space(1))) void*)(srcB_ + (size_t)row_ * 1024 + slot_ * 16), \
                (__attribute__((address_space(3))) void*)(dstB_ + c0_ * 16), 16, 0, 0); \
        }                                                        \
    } while (0)

    f32x4 acc[4][8];
#pragma unroll
    for (int m = 0; m < 4; ++m)
#pragma unroll
        for (int n = 0; n < 8; ++n) acc[m][n] = f32x4{0.f, 0.f, 0.f, 0.f};

#define COMPUTE(scur) do {                                                    \
        const char* Bcur_ = smem + (((scur) & 1) << 16);                      \
        _Pragma("unroll")                                                     \
        for (int ksub_ = 0; ksub_ < 2; ++ksub_) {                             \
            bf16x8 bv_[8];                                                    \
            _Pragma("unroll")                                                 \
            for (int n_ = 0; n_ < 8; ++n_) {                                  \
                int row_ = wc * 128 + n_ * 16 + lrow;                         \
                bv_[n_] = *reinterpret_cast<const bf16x8*>(                   \
                    Bcur_ + row_ * 128 + ((ksub_ * 64 + lq * 16) ^ swzR));    \
            }                                                                 \
            _Pragma("unroll")                                                 \
            for (int m_ = 0; m_ < 4; ++m_) {                                  \
                int row_ = wr * 64 + m_ * 16 + lrow;                          \
                bf16x8 av_ = *reinterpret_cast<const bf16x8*>(                \
                    Abuf + row_ * 128 + ((ksub_ * 64 + lq * 16) ^ swzR));     \
                _Pragma("unroll")                                             \
                for (int n_ = 0; n_ < 8; ++n_)                                \
                    acc[m_][n_] = __builtin_amdgcn_mfma_f32_16x16x32_bf16(    \
                        av_, bv_[n_], acc[m_][n_], 0, 0, 0);                  \
            }                                                                 \
        }                                                                     \
    } while (0)

    // ---- prologue: A(0) regs, B(0) glds, A(1) regs in flight ----
    LOAD_A(0, rA0);          // 4
    STAGE_B(0);              // 8
    LOAD_A(1, rA1);          // 4  -> 16 outstanding (+ early const loads, older)
    VMCNT(12);               // A(0) regs ready
    WRITE_A(rA0);
    VMCNT(4);                // B(0) in LDS; A(1) stays in flight
    LGKM0; SCHED0;
    SBAR;

    // ---- steady steps (fully unrolled; A(u) in reg set u&1) ----
#define STEP_MID(s, Rcons, Rload)                                \
    COMPUTE(s);                                                  \
    SBAR;                                                        \
    STAGE_B((s) + 1);                                            \
    LOAD_A((s) + 2, Rload);                                      \
    VMCNT(12);               /* A(s+1) regs ready */             \
    WRITE_A(Rcons);                                              \
    VMCNT(4);                /* B(s+1) landed; A(s+2) in flight */\
    LGKM0; SCHED0;                                               \
    SBAR

    STEP_MID(0, rA1, rA0);
    STEP_MID(1, rA0, rA1);
    STEP_MID(2, rA1, rA0);
    STEP_MID(3, rA0, rA1);
    STEP_MID(4, rA1, rA0);
    STEP_MID(5, rA0, rA1);

    // s=6: stage B(7) only; A(7) already in rA1
    COMPUTE(6);
    SBAR;
    STAGE_B(7);
    VMCNT(8);                // A(7) regs ready (B(7)'s 8 remain)
    WRITE_A(rA1);
    VMCNT(0);                // B(7) landed
    LGKM0; SCHED0;
    SBAR;

    COMPUTE(7);
    __syncthreads();

    // ---- epilogue: pscore += w_out * tanh(qh + relu(acc)) ----
    float pscore[4][4] = {};
#pragma unroll
    for (int n = 0; n < 8; ++n) {
        float wo = wo_r[n];
        float qv = qh_r[n];
#pragma unroll
        for (int m = 0; m < 4; ++m)
#pragma unroll
            for (int r = 0; r < 4; ++r) {
                float x = qv + fmaxf(acc[m][n][r], 0.f);
                pscore[m][r] = fmaf(wo, tanh_fast(x), pscore[m][r]);
            }
    }

    // ---- cross-lane (16 g-cols) then cross-wave (4 wc) score reduction ----
#pragma unroll
    for (int m = 0; m < 4; ++m)
#pragma unroll
        for (int r = 0; r < 4; ++r) {
            float v = pscore[m][r];
            v += __shfl_xor(v, 1);
            v += __shfl_xor(v, 2);
            v += __shfl_xor(v, 4);
            v += __shfl_xor(v, 8);
            if (lrow == 0)
                sscore[wc * 128 + wr * 64 + m * 16 + lq * 4 + r] = v;
        }
    __syncthreads();

    // ---- w_t = exp(s_t) (no max-sub: |s| <= Sum|w_out| ~ 15, exact shift) ----
    if (tid < 128)
        wlds[tid] = __expf(sscore[0 * 128 + tid] + sscore[1 * 128 + tid] +
                           sscore[2 * 128 + tid] + sscore[3 * 128 + tid]);
    __syncthreads();

    // ---- psum (wave 0) + weighted key sum (h = tid; key tile L2/L3-hot) ----
    if (wid == 0) {
        float v = wlds[lane] + wlds[lane + 64];
        v += __shfl_xor(v, 1);
        v += __shfl_xor(v, 2);
        v += __shfl_xor(v, 4);
        v += __shfl_xor(v, 8);
        v += __shfl_xor(v, 16);
        v += __shfl_xor(v, 32);
        if (lane == 0) psum[b * 16 + chnk] = v;
    }
    const float* keyp = key + ((size_t)b * T_N + t0) * H_N + tid;
    float a0 = 0.f;
#pragma unroll 8
    for (int t = 0; t < 128; ++t)
        a0 = fmaf(wlds[t], keyp[(size_t)t * H_N], a0);
    partial[((size_t)(b * 16 + chnk)) * H_N + tid] = a0;

#undef LOAD_A
#undef WRITE_A
#undef STAGE_B
#undef COMPUTE
#undef STEP_MID
}

// ---------------------------------------------------------------------------
// K4: out[b][h] = (sum_c partial[b][c][h]) / (sum_c psum[b][c])
// ---------------------------------------------------------------------------
__global__ void k_out(const float* __restrict__ partial, const float* __restrict__ psum,
                      float* __restrict__ out) {
    int idx = blockIdx.x * 256 + threadIdx.x;   // 65536 outputs
    int b = idx >> 9, h = idx & 511;
    float s = 0.f, d = 0.f;
#pragma unroll
    for (int c = 0; c < 16; ++c) {
        s += partial[((size_t)(b * 16 + c)) * H_N + h];
        d += psum[b * 16 + c];
    }
    out[idx] = s / d;
}

extern "C" void kernel_launch(void* const* d_in, const int* in_sizes, int n_in,
                              void* d_out, int out_size, void* d_ws, size_t ws_size,
                              hipStream_t stream) {
    const float* query = (const float*)d_in[0];
    const float* key   = (const float*)d_in[1];
    const float* w1    = (const float*)d_in[2];
    const float* w2    = (const float*)d_in[3];
    const float* w_out = (const float*)d_in[4];
    float* out = (float*)d_out;

    char* ws = (char*)d_ws;
    unsigned short* w2sw = (unsigned short*)(ws);            // 512 KB
    float* qh      = (float*)(ws + 524288);                  // 256 KB
    float* partial = (float*)(ws + 1048576);                 // 4 MB
    float* psum    = (float*)(ws + 5242880);                 // 8 KB

    hipLaunchKernelGGL(k_w2prep, dim3(128),     dim3(256), 0, stream, w2, w2sw);
    hipLaunchKernelGGL(k_qh,     dim3(128),     dim3(512), 0, stream, query, w1, qh);
    hipLaunchKernelGGL(k_scores, dim3(16, 128), dim3(512), 0, stream,
                       key, w2sw, qh, w_out, partial, psum);
    hipLaunchKernelGGL(k_out,    dim3(256),     dim3(256), 0, stream, partial, psum, out);
}

// Round 7
// 383.247 us; speedup vs baseline: 1.1878x; 1.1878x over previous
//
#include <hip/hip_runtime.h>
#include <hip/hip_bf16.h>

#define B_N 128
#define T_N 2048
#define H_N 512

typedef __attribute__((ext_vector_type(8))) short bf16x8;   // 8 bf16 = 4 VGPRs
typedef __attribute__((ext_vector_type(4))) float f32x4;    // MFMA acc

union U4 { unsigned int i[4]; bf16x8 v; };

// RNE f32 -> bf16 (low 16 bits)
__device__ __forceinline__ unsigned int f2bf(float f) {
    unsigned int u = __float_as_uint(f);
    u += 0x7fffu + ((u >> 16) & 1u);
    return u >> 16;
}

// packed f32x2 -> bf16x2 (RNE), single VALU inst
__device__ __forceinline__ unsigned int cvtpk(float lo, float hi) {
    unsigned int r;
    asm("v_cvt_pk_bf16_f32 %0, %1, %2" : "=v"(r) : "v"(lo), "v"(hi));
    return r;
}

// x >= 0 always here (relu+relu)
__device__ __forceinline__ float tanh_fast(float x) {
    float e = __expf(2.f * x);
    float r = __builtin_amdgcn_rcpf(e + 1.f);
    return 1.f - 2.f * r;
}

#define FENCE asm volatile("" ::: "memory")
#define SBAR  do { FENCE; __builtin_amdgcn_s_barrier(); FENCE; } while (0)
#define VMCNT(n) asm volatile("s_waitcnt vmcnt(" #n ")" ::: "memory")
#define LGKM0    asm volatile("s_waitcnt lgkmcnt(0)" ::: "memory")
#define SCHED0   __builtin_amdgcn_sched_barrier(0)

// ---------------------------------------------------------------------------
// K2: w2 (512x512 f32) -> bf16, pre-swizzled within each 1024B row:
// dst_byte(g,k) = g*1024 + ((k*2) ^ ((g&7)<<4)). Staged LINEARLY into LDS;
// fragment read applies byte^((row&7)<<4), cancelling (even swizzle count).
// ---------------------------------------------------------------------------
__global__ void k_w2prep(const float* __restrict__ w2, unsigned short* __restrict__ w2sw) {
    int c = blockIdx.x * 256 + threadIdx.x;      // 32768 chunks of 8 elems
    int g = c >> 6, kc = c & 63;
    const float4* s = reinterpret_cast<const float4*>(w2 + (size_t)g * H_N + kc * 8);
    float4 f0 = s[0], f1 = s[1];
    uint4 p;
    p.x = f2bf(f0.x) | (f2bf(f0.y) << 16);
    p.y = f2bf(f0.z) | (f2bf(f0.w) << 16);
    p.z = f2bf(f1.x) | (f2bf(f1.y) << 16);
    p.w = f2bf(f1.z) | (f2bf(f1.w) << 16);
    *reinterpret_cast<uint4*>(reinterpret_cast<char*>(w2sw) + (size_t)g * 1024 +
                              (((kc * 16) ^ ((g & 7) << 4)))) = p;
}

// ---------------------------------------------------------------------------
// K1: q_h[b][g] = relu(query[b]·w1[g])   (f32, tiny; w1 L2-resident)
// ---------------------------------------------------------------------------
__global__ void k_qh(const float* __restrict__ query, const float* __restrict__ w1,
                     float* __restrict__ qh) {
    int b = blockIdx.x;
    int g = threadIdx.x;                          // 512 threads
    __shared__ float q[H_N];
    q[g] = query[(size_t)b * H_N + g];
    __syncthreads();
    const float4* w = reinterpret_cast<const float4*>(w1 + (size_t)g * H_N);
    float acc = 0.f;
#pragma unroll 4
    for (int i = 0; i < H_N / 4; ++i) {
        float4 wv = w[i];
        acc += q[4*i] * wv.x + q[4*i+1] * wv.y + q[4*i+2] * wv.z + q[4*i+3] * wv.w;
    }
    qh[(size_t)b * H_N + g] = fmaxf(acc, 0.f);
}

// ---------------------------------------------------------------------------
// K3 (fused): per block of 128 t-rows:
//   s_t = sum_g w_out[g]*tanh(qh[b][g] + relu(key[b][t]·w2[g]))  -> w_t=exp(s_t)
//   psum[b][c] = sum_t w_t ;  partial[b][c][h] = sum_t w_t*key[t][h]
// BM=128, BN=512 (single sweep, key fetched once), BK=64, 8 steps.
// 8 waves 2wr x 4wc, wave tile 64t x 128g (4m x 8n frags of 16x16x32).
// Pipeline (all buffers TWO steps deep, one wait per step):
//   A (key, HBM): f32 global->regs issued at step s-2; cvt_pk + ds_write into
//     bf16 LDS dbuf (2x16KB) at step s-1; consumed at step s.
//   B (w2sw, L2): glds into LDS dbuf (2x64KB), issued at step s-2.
// Steady step: COMPUTE(s) | SBAR | STAGE_B(s+2),LOAD_A(s+2) | VMCNT(12)
//   [= A(s+1) regs ready AND B(s+1) landed, both issued a FULL step ago]
//   | WRITE_A(s+1) | LGKM0 | SBAR. Never vmcnt(0) mid-loop.
// LDS 160KB (full pool) -> 1 block/CU. Loop arch-VGPR kept < 128 (epilogue
// constants loaded AFTER the loop) to avoid r6's scratch spill.
// ---------------------------------------------------------------------------
__global__ __launch_bounds__(512, 2) void k_scores(
    const float* __restrict__ key, const unsigned short* __restrict__ w2sw,
    const float* __restrict__ qh, const float* __restrict__ w_out,
    float* __restrict__ partial, float* __restrict__ psum)
{
    const int b    = blockIdx.y;
    const int chnk = blockIdx.x;
    const int t0   = chnk * 128;
    const int tid  = threadIdx.x;
    const int wid  = tid >> 6;
    const int lane = tid & 63;
    const int lrow = lane & 15;        // fragment row/col
    const int lq   = lane >> 4;        // 0..3 k-group
    const int wr   = wid >> 2;         // 0..1 t half (64 rows)
    const int wc   = wid & 3;          // 0..3 g quarter (128 g)
    const int swzR = (lrow & 7) << 4;  // byte XOR for fragment reads

    // [0,128K): B bf16 dbuf (2 x 512rows x 64k); [128K,160K): A bf16 dbuf (2 x 128x64)
    __shared__ __align__(16) char smem[163840];
    char* Abase = smem + 131072;
    float* sscore = reinterpret_cast<float*>(smem);          // post-loop alias
    float* wlds   = reinterpret_cast<float*>(smem + 2048);   // post-loop alias

    const char* keybB = reinterpret_cast<const char*>(key + ((size_t)b * T_N + t0) * H_N);
    const char* w2sb  = reinterpret_cast<const char*>(w2sw);

    // A staging geometry: thread -> (row = tid>>2, 16 contiguous k at (tid&3)*16)
    const int arow = tid >> 2;
    const int acol = tid & 3;
    const char* asrc = keybB + (size_t)arow * 2048 + acol * 64;   // 64B = 16 f32
    const int awb0 = arow * 128 + ((acol * 32)      ^ ((arow & 7) << 4));
    const int awb1 = arow * 128 + ((acol * 32 + 16) ^ ((arow & 7) << 4));

    float4 rA0[4], rA1[4];   // pipeline reg sets: A(u) lives in set (u&1)

#define LOAD_A(u, R) do {                                        \
        const char* p_ = asrc + ((u) << 8);                      \
        R[0] = *reinterpret_cast<const float4*>(p_);             \
        R[1] = *reinterpret_cast<const float4*>(p_ + 16);        \
        R[2] = *reinterpret_cast<const float4*>(p_ + 32);        \
        R[3] = *reinterpret_cast<const float4*>(p_ + 48);        \
    } while (0)

    // write A(u) (regs R) into Abuf (u&1), XOR-swizzled bf16 rows (0-conflict)
#define WRITE_A(u, R) do {                                       \
        char* ab_ = Abase + (((u) & 1) << 14);                   \
        U4 u0_, u1_;                                             \
        u0_.i[0] = cvtpk(R[0].x, R[0].y);                        \
        u0_.i[1] = cvtpk(R[0].z, R[0].w);                        \
        u0_.i[2] = cvtpk(R[1].x, R[1].y);                        \
        u0_.i[3] = cvtpk(R[1].z, R[1].w);                        \
        u1_.i[0] = cvtpk(R[2].x, R[2].y);                        \
        u1_.i[1] = cvtpk(R[2].z, R[2].w);                        \
        u1_.i[2] = cvtpk(R[3].x, R[3].y);                        \
        u1_.i[3] = cvtpk(R[3].z, R[3].w);                        \
        *reinterpret_cast<bf16x8*>(ab_ + awb0) = u0_.v;          \
        *reinterpret_cast<bf16x8*>(ab_ + awb1) = u1_.v;          \
    } while (0)

    // B tile u: all 512 g-rows, bf16 k-cols [u*64,+64) -> Bbuf (u&1), linear
#define STAGE_B(u) do {                                          \
        char* dstB_ = smem + (((u) & 1) << 16);                  \
        const char* srcB_ = w2sb + ((u) << 7);                   \
        _Pragma("unroll")                                        \
        for (int i_ = 0; i_ < 8; ++i_) {                         \
            int c0_ = i_ * 512 + wid * 64;                       \
            int c_  = c0_ + lane;                                \
            int row_ = c_ >> 3, slot_ = c_ & 7;                  \
            __builtin_amdgcn_global_load_lds(                    \
                (const __attribute__((address_space(1))) void*)(srcB_ + (size_t)row_ * 1024 + slot_ * 16), \
                (__attribute__((address_space(3))) void*)(dstB_ + c0_ * 16), 16, 0, 0); \
        }                                                        \
    } while (0)

    f32x4 acc[4][8];
#pragma unroll
    for (int m = 0; m < 4; ++m)
#pragma unroll
        for (int n = 0; n < 8; ++n) acc[m][n] = f32x4{0.f, 0.f, 0.f, 0.f};

#define COMPUTE(scur) do {                                                    \
        const char* Bcur_ = smem + (((scur) & 1) << 16);                      \
        const char* Acur_ = Abase + (((scur) & 1) << 14);                     \
        _Pragma("unroll")                                                     \
        for (int ksub_ = 0; ksub_ < 2; ++ksub_) {                             \
            bf16x8 bv_[8];                                                    \
            _Pragma("unroll")                                                 \
            for (int n_ = 0; n_ < 8; ++n_) {                                  \
                int row_ = wc * 128 + n_ * 16 + lrow;                         \
                bv_[n_] = *reinterpret_cast<const bf16x8*>(                   \
                    Bcur_ + row_ * 128 + ((ksub_ * 64 + lq * 16) ^ swzR));    \
            }                                                                 \
            _Pragma("unroll")                                                 \
            for (int m_ = 0; m_ < 4; ++m_) {                                  \
                int row_ = wr * 64 + m_ * 16 + lrow;                          \
                bf16x8 av_ = *reinterpret_cast<const bf16x8*>(                \
                    Acur_ + row_ * 128 + ((ksub_ * 64 + lq * 16) ^ swzR));    \
                _Pragma("unroll")                                             \
                for (int n_ = 0; n_ < 8; ++n_)                                \
                    acc[m_][n_] = __builtin_amdgcn_mfma_f32_16x16x32_bf16(    \
                        av_, bv_[n_], acc[m_][n_], 0, 0, 0);                  \
            }                                                                 \
        }                                                                     \
    } while (0)

    // ---- prologue: A0,B0,A1,B1 issued (24 outstanding) ----
    LOAD_A(0, rA0);          // 4
    STAGE_B(0);              // 8
    LOAD_A(1, rA1);          // 4
    STAGE_B(1);              // 8
    VMCNT(20);               // A(0) regs ready
    WRITE_A(0, rA0);
    VMCNT(12);               // B(0) landed; A(1)+B(1) stay in flight
    LGKM0; SCHED0;
    SBAR;

    // ---- steady steps: one VMCNT(12), both waited groups issued a step ago ----
#define STEP_MID(s, Rload, Rcons)                                \
    COMPUTE(s);                                                  \
    SBAR;                    /* Bbuf(s&1)+Abuf((s+1)&1) free */  \
    STAGE_B((s) + 2);                                            \
    LOAD_A((s) + 2, Rload);                                      \
    VMCNT(12);               /* A(s+1) regs + B(s+1) landed */   \
    WRITE_A((s) + 1, Rcons);                                     \
    LGKM0; SCHED0;                                               \
    SBAR

    STEP_MID(0, rA0, rA1);
    STEP_MID(1, rA1, rA0);
    STEP_MID(2, rA0, rA1);
    STEP_MID(3, rA1, rA0);
    STEP_MID(4, rA0, rA1);
    STEP_MID(5, rA1, rA0);

    // s=6: nothing left to issue; drain A(7)+B(7)
    COMPUTE(6);
    SBAR;
    VMCNT(0);
    WRITE_A(7, rA1);
    LGKM0; SCHED0;
    SBAR;

    COMPUTE(7);
    __syncthreads();

    // ---- epilogue: pscore += w_out * tanh(qh + relu(acc)) ----
    // (constants loaded HERE, not across the loop -> no loop VGPR pressure)
    float pscore[4][4] = {};
#pragma unroll
    for (int n = 0; n < 8; ++n) {
        int g = wc * 128 + n * 16 + lrow;
        float wo = w_out[g];
        float qv = qh[(size_t)b * H_N + g];
#pragma unroll
        for (int m = 0; m < 4; ++m)
#pragma unroll
            for (int r = 0; r < 4; ++r) {
                float x = qv + fmaxf(acc[m][n][r], 0.f);
                pscore[m][r] = fmaf(wo, tanh_fast(x), pscore[m][r]);
            }
    }

    // ---- cross-lane (16 g-cols) then cross-wave (4 wc) score reduction ----
#pragma unroll
    for (int m = 0; m < 4; ++m)
#pragma unroll
        for (int r = 0; r < 4; ++r) {
            float v = pscore[m][r];
            v += __shfl_xor(v, 1);
            v += __shfl_xor(v, 2);
            v += __shfl_xor(v, 4);
            v += __shfl_xor(v, 8);
            if (lrow == 0)
                sscore[wc * 128 + wr * 64 + m * 16 + lq * 4 + r] = v;
        }
    __syncthreads();

    // ---- w_t = exp(s_t) (no max-sub: |s| <= Sum|w_out| ~ 15, exact shift) ----
    if (tid < 128)
        wlds[tid] = __expf(sscore[0 * 128 + tid] + sscore[1 * 128 + tid] +
                           sscore[2 * 128 + tid] + sscore[3 * 128 + tid]);
    __syncthreads();

    // ---- psum (wave 0) + weighted key sum (h = tid; key tile L2/L3-hot) ----
    if (wid == 0) {
        float v = wlds[lane] + wlds[lane + 64];
        v += __shfl_xor(v, 1);
        v += __shfl_xor(v, 2);
        v += __shfl_xor(v, 4);
        v += __shfl_xor(v, 8);
        v += __shfl_xor(v, 16);
        v += __shfl_xor(v, 32);
        if (lane == 0) psum[b * 16 + chnk] = v;
    }
    const float* keyp = key + ((size_t)b * T_N + t0) * H_N + tid;
    float a0 = 0.f;
#pragma unroll 8
    for (int t = 0; t < 128; ++t)
        a0 = fmaf(wlds[t], keyp[(size_t)t * H_N], a0);
    partial[((size_t)(b * 16 + chnk)) * H_N + tid] = a0;

#undef LOAD_A
#undef WRITE_A
#undef STAGE_B
#undef COMPUTE
#undef STEP_MID
}

// ---------------------------------------------------------------------------
// K4: out[b][h] = (sum_c partial[b][c][h]) / (sum_c psum[b][c])
// ---------------------------------------------------------------------------
__global__ void k_out(const float* __restrict__ partial, const float* __restrict__ psum,
                      float* __restrict__ out) {
    int idx = blockIdx.x * 256 + threadIdx.x;   // 65536 outputs
    int b = idx >> 9, h = idx & 511;
    float s = 0.f, d = 0.f;
#pragma unroll
    for (int c = 0; c < 16; ++c) {
        s += partial[((size_t)(b * 16 + c)) * H_N + h];
        d += psum[b * 16 + c];
    }
    out[idx] = s / d;
}

extern "C" void kernel_launch(void* const* d_in, const int* in_sizes, int n_in,
                              void* d_out, int out_size, void* d_ws, size_t ws_size,
                              hipStream_t stream) {
    const float* query = (const float*)d_in[0];
    const float* key   = (const float*)d_in[1];
    const float* w1    = (const float*)d_in[2];
    const float* w2    = (const float*)d_in[3];
    const float* w_out = (const float*)d_in[4];
    float* out = (float*)d_out;

    char* ws = (char*)d_ws;
    unsigned short* w2sw = (unsigned short*)(ws);            // 512 KB
    float* qh      = (float*)(ws + 524288);                  // 256 KB
    float* partial = (float*)(ws + 1048576);                 // 4 MB
    float* psum    = (float*)(ws + 5242880);                 // 8 KB

    hipLaunchKernelGGL(k_w2prep, dim3(128),     dim3(256), 0, stream, w2, w2sw);
    hipLaunchKernelGGL(k_qh,     dim3(128),     dim3(512), 0, stream, query, w1, qh);
    hipLaunchKernelGGL(k_scores, dim3(16, 128), dim3(512), 0, stream,
                       key, w2sw, qh, w_out, partial, psum);
    hipLaunchKernelGGL(k_out,    dim3(256),     dim3(256), 0, stream, partial, psum, out);
}

// Round 8
// 337.985 us; speedup vs baseline: 1.3468x; 1.1339x over previous
//
#include <hip/hip_runtime.h>
#include <hip/hip_bf16.h>

#define B_N 128
#define T_N 2048
#define H_N 512

typedef __attribute__((ext_vector_type(8))) short bf16x8;   // 8 bf16 = 4 VGPRs
typedef __attribute__((ext_vector_type(4))) float f32x4;    // MFMA acc

union U4 { unsigned int i[4]; bf16x8 v; };

// RNE f32 -> bf16 (low 16 bits)
__device__ __forceinline__ unsigned int f2bf(float f) {
    unsigned int u = __float_as_uint(f);
    u += 0x7fffu + ((u >> 16) & 1u);
    return u >> 16;
}

// packed f32x2 -> bf16x2 (RNE), single VALU inst
__device__ __forceinline__ unsigned int cvtpk(float lo, float hi) {
    unsigned int r;
    asm("v_cvt_pk_bf16_f32 %0, %1, %2" : "=v"(r) : "v"(lo), "v"(hi));
    return r;
}

// x >= 0 always here (relu+relu)
__device__ __forceinline__ float tanh_fast(float x) {
    float e = __expf(2.f * x);
    float r = __builtin_amdgcn_rcpf(e + 1.f);
    return 1.f - 2.f * r;
}

#define FENCE asm volatile("" ::: "memory")
#define SBAR  do { FENCE; __builtin_amdgcn_s_barrier(); FENCE; } while (0)
#define VMCNT(n) asm volatile("s_waitcnt vmcnt(" #n ")" ::: "memory")
#define LGKM0    asm volatile("s_waitcnt lgkmcnt(0)" ::: "memory")
#define SCHED0   __builtin_amdgcn_sched_barrier(0)

// ---------------------------------------------------------------------------
// K2: w2 (512x512 f32) -> bf16, pre-swizzled within each 1024B row:
// dst_byte(g,k) = g*1024 + ((k*2) ^ ((g&7)<<4)).  XOR stays inside each 128B
// k-slice, so any 128B-slice copy is linear; fragment read applies
// byte^((row&7)<<4), cancelling (even swizzle count along the path).
// ---------------------------------------------------------------------------
__global__ void k_w2prep(const float* __restrict__ w2, unsigned short* __restrict__ w2sw) {
    int c = blockIdx.x * 256 + threadIdx.x;      // 32768 chunks of 8 elems
    int g = c >> 6, kc = c & 63;
    const float4* s = reinterpret_cast<const float4*>(w2 + (size_t)g * H_N + kc * 8);
    float4 f0 = s[0], f1 = s[1];
    uint4 p;
    p.x = f2bf(f0.x) | (f2bf(f0.y) << 16);
    p.y = f2bf(f0.z) | (f2bf(f0.w) << 16);
    p.z = f2bf(f1.x) | (f2bf(f1.y) << 16);
    p.w = f2bf(f1.z) | (f2bf(f1.w) << 16);
    *reinterpret_cast<uint4*>(reinterpret_cast<char*>(w2sw) + (size_t)g * 1024 +
                              (((kc * 16) ^ ((g & 7) << 4)))) = p;
}

// ---------------------------------------------------------------------------
// K1: q_h[b][g] = relu(query[b]·w1[g])   (f32, tiny; w1 L2-resident)
// ---------------------------------------------------------------------------
__global__ void k_qh(const float* __restrict__ query, const float* __restrict__ w1,
                     float* __restrict__ qh) {
    int b = blockIdx.x;
    int g = threadIdx.x;                          // 512 threads
    __shared__ float q[H_N];
    q[g] = query[(size_t)b * H_N + g];
    __syncthreads();
    const float4* w = reinterpret_cast<const float4*>(w1 + (size_t)g * H_N);
    float acc = 0.f;
#pragma unroll 4
    for (int i = 0; i < H_N / 4; ++i) {
        float4 wv = w[i];
        acc += q[4*i] * wv.x + q[4*i+1] * wv.y + q[4*i+2] * wv.z + q[4*i+3] * wv.w;
    }
    qh[(size_t)b * H_N + g] = fmaxf(acc, 0.f);
}

// ---------------------------------------------------------------------------
// K3 (fused): per block of 64 t-rows (BM=64, 32 chunks x 128 b = 4096 blocks):
//   s_t = sum_g w_out[g]*tanh(qh[b][g] + relu(key[b][t]·w2[g]))  -> w_t=exp(s_t)
//   psum[b][c] = sum_t w_t ;  partial[b][c][h] = sum_t w_t * key_bf16[t][h]
// GEMM: 2 g-sweeps of BN=256, BK=64, 16 steps. 8 waves 2wr x 4wc, wave tile
// 32t x 64g -> acc[2][4] = 32 regs/lane (NO spill: 256-reg cap, r6/r7 bug).
//   A (key, HBM): f32 global->regs 2 steps ahead, cvt_pk -> FULL-K padded
//     LDS tile [64][520] bf16 (65KB, +16B/row pad = 2-way free). Written once
//     per k-slice in sweep 0; sweep 1 AND the PV tail re-read it from LDS
//     (key fetched from HBM exactly once, PV tail is LDS-speed).
//   B (w2sw, L2): 256x64 bf16 tiles, 2x32KB dbuf via global_load_lds
//     (linear copy of pre-swizzled slices), issued 2 steps ahead.
// Counted vmcnt only (never 0 mid-loop): steady VMCNT(6) = A(s+1) regs +
// B(s+1) landed, both issued a full step earlier. LDS 129KB -> 1 block/CU.
// ---------------------------------------------------------------------------
__global__ __launch_bounds__(512, 2) void k_scores(
    const float* __restrict__ key, const unsigned short* __restrict__ w2sw,
    const float* __restrict__ qh, const float* __restrict__ w_out,
    float* __restrict__ partial, float* __restrict__ psum)
{
    const int b    = blockIdx.y;
    const int chnk = blockIdx.x;
    const int t0   = chnk * 64;
    const int tid  = threadIdx.x;
    const int wid  = tid >> 6;
    const int lane = tid & 63;
    const int lrow = lane & 15;        // fragment row/col
    const int lq   = lane >> 4;        // 0..3 k-group
    const int wr   = wid >> 2;         // 0..1 t half (32 rows)
    const int wc   = wid & 3;          // 0..3 g quarter (64 g of 256)
    const int swzB = (lrow & 7) << 4;  // byte XOR for B fragment reads

    // [0,64K): B bf16 dbuf (2 x 256rows x 128B); [64K, 64K+66560): A bf16 [64][1040B]
    __shared__ __align__(16) char smem[131072 + 1024];  // 65536*2? no: 64K B + 65K A
    char* Bbase = smem;                       // 2 x 32768
    char* Abase = smem + 65536;               // 64 rows x 1040 B = 66560
    float* sscore = reinterpret_cast<float*>(smem);          // post-loop alias (buf0)
    float* wlds   = reinterpret_cast<float*>(smem + 2048);   // post-loop alias

    const char* keybB = reinterpret_cast<const char*>(key + ((size_t)b * T_N + t0) * H_N);
    const char* w2sb  = reinterpret_cast<const char*>(w2sw);

    // ---- preload epilogue constants (oldest vmem; safe for counted waits) ----
    float wo_r[2][4], qh_r[2][4];
#pragma unroll
    for (int sw = 0; sw < 2; ++sw)
#pragma unroll
        for (int n = 0; n < 4; ++n) {
            int g = sw * 256 + wc * 64 + n * 16 + lrow;
            wo_r[sw][n] = w_out[g];
            qh_r[sw][n] = qh[(size_t)b * H_N + g];
        }

    // A staging: thread -> (row = tid>>3 in 0..63, 32B f32 chunk acol = tid&7)
    const int arow = tid >> 3;
    const int acol = tid & 7;
    const char* asrc = keybB + (size_t)arow * 2048 + acol * 32;   // 32B = 8 f32
    char* adst = Abase + arow * 1040 + acol * 16;                 // 16B bf16

    float4 rA0[2], rA1[2];   // pipeline reg sets: A(u) lives in set (u&1)

#define LOAD_A(u, R) do {                                        \
        const char* p_ = asrc + ((u) << 8);                      \
        R[0] = *reinterpret_cast<const float4*>(p_);             \
        R[1] = *reinterpret_cast<const float4*>(p_ + 16);        \
    } while (0)

#define WRITE_A(u, R) do {                                       \
        U4 u0_;                                                  \
        u0_.i[0] = cvtpk(R[0].x, R[0].y);                        \
        u0_.i[1] = cvtpk(R[0].z, R[0].w);                        \
        u0_.i[2] = cvtpk(R[1].x, R[1].y);                        \
        u0_.i[3] = cvtpk(R[1].z, R[1].w);                        \
        *reinterpret_cast<bf16x8*>(adst + ((u) << 7)) = u0_.v;   \
    } while (0)

    // B tile u: g rows [(u>>3)*256,+256), bf16 k slice [(u&7)*64,+64) -> buf u&1
#define STAGE_B(u) do {                                          \
        char* dstB_ = Bbase + (((u) & 1) << 15);                 \
        const char* srcB_ = w2sb + (((u) >> 3) << 18) + (((u) & 7) << 7); \
        _Pragma("unroll")                                        \
        for (int i_ = 0; i_ < 4; ++i_) {                         \
            int c0_ = i_ * 512 + wid * 64;                       \
            int c_  = c0_ + lane;                                \
            int row_ = c_ >> 3, slot_ = c_ & 7;                  \
            __builtin_amdgcn_global_load_lds(                    \
                (const __attribute__((address_space(1))) void*)(srcB_ + (size_t)row_ * 1024 + slot_ * 16), \
                (__attribute__((address_space(3))) void*)(dstB_ + c0_ * 16), 16, 0, 0); \
        }                                                        \
    } while (0)

    f32x4 acc[2][4];
#pragma unroll
    for (int m = 0; m < 2; ++m)
#pragma unroll
        for (int n = 0; n < 4; ++n) acc[m][n] = f32x4{0.f, 0.f, 0.f, 0.f};
    float pscore[2][4] = {};        // [m][r] partials over all g

    // compute step s: A slice ks = s&7 from padded tile, B from buf s&1
#define COMPUTE(s) do {                                                       \
        const char* Bcur_ = Bbase + (((s) & 1) << 15);                        \
        const int kA_ = ((s) & 7) << 7;                                       \
        _Pragma("unroll")                                                     \
        for (int ksub_ = 0; ksub_ < 2; ++ksub_) {                             \
            bf16x8 bv_[4];                                                    \
            _Pragma("unroll")                                                 \
            for (int n_ = 0; n_ < 4; ++n_) {                                  \
                int row_ = wc * 64 + n_ * 16 + lrow;                          \
                bv_[n_] = *reinterpret_cast<const bf16x8*>(                   \
                    Bcur_ + row_ * 128 + ((ksub_ * 64 + lq * 16) ^ swzB));    \
            }                                                                 \
            _Pragma("unroll")                                                 \
            for (int m_ = 0; m_ < 2; ++m_) {                                  \
                int row_ = wr * 32 + m_ * 16 + lrow;                          \
                bf16x8 av_ = *reinterpret_cast<const bf16x8*>(                \
                    Abase + row_ * 1040 + kA_ + ksub_ * 64 + lq * 16);        \
                _Pragma("unroll")                                             \
                for (int n_ = 0; n_ < 4; ++n_)                                \
                    acc[m_][n_] = __builtin_amdgcn_mfma_f32_16x16x32_bf16(    \
                        av_, bv_[n_], acc[m_][n_], 0, 0, 0);                  \
            }                                                                 \
        }                                                                     \
    } while (0)

#define EPILOG(sw) do {                                                       \
        _Pragma("unroll")                                                     \
        for (int n_ = 0; n_ < 4; ++n_) {                                      \
            float wo_ = wo_r[sw][n_];                                         \
            float qv_ = qh_r[sw][n_];                                         \
            _Pragma("unroll")                                                 \
            for (int m_ = 0; m_ < 2; ++m_) {                                  \
                _Pragma("unroll")                                             \
                for (int r_ = 0; r_ < 4; ++r_) {                              \
                    float x_ = qv_ + fmaxf(acc[m_][n_][r_], 0.f);             \
                    pscore[m_][r_] = fmaf(wo_, tanh_fast(x_), pscore[m_][r_]);\
                }                                                             \
                acc[m_][n_] = f32x4{0.f, 0.f, 0.f, 0.f};                      \
            }                                                                 \
        }                                                                     \
    } while (0)

    // ---- prologue: A0,B0,A1,B1 issued (12 outstanding) ----
    LOAD_A(0, rA0);          // 2
    STAGE_B(0);              // 4
    LOAD_A(1, rA1);          // 2
    STAGE_B(1);              // 4
    VMCNT(10);               // A(0) regs ready (also drains the const preloads)
    WRITE_A(0, rA0);
    VMCNT(6);                // B(0) landed; A(1)+B(1) stay in flight
    LGKM0; SCHED0;
    SBAR;

#define STEP_MID(s, Rload, Rcons)                                \
    COMPUTE(s);                                                  \
    SBAR;                    /* Bbuf(s&1) free; A slice s+1 unread */ \
    STAGE_B((s) + 2);                                            \
    LOAD_A((s) + 2, Rload);                                      \
    VMCNT(6);                /* A(s+1) regs + B(s+1) landed */   \
    WRITE_A((s) + 1, Rcons);                                     \
    LGKM0; SCHED0;                                               \
    SBAR

    STEP_MID(0, rA0, rA1);
    STEP_MID(1, rA1, rA0);
    STEP_MID(2, rA0, rA1);
    STEP_MID(3, rA1, rA0);
    STEP_MID(4, rA0, rA1);
    STEP_MID(5, rA1, rA0);

    // s=6: last A write; B pipeline rolls into sweep 1
    COMPUTE(6);
    SBAR;
    STAGE_B(8);
    VMCNT(4);                // A(7) regs + B(7) landed; B(8) in flight
    WRITE_A(7, rA1);
    LGKM0; SCHED0;
    SBAR;

    // s=7: end of sweep 0; epilogue overlaps B(8)/B(9) DMA
    COMPUTE(7);
    SBAR;
    STAGE_B(9);
    EPILOG(0);
    VMCNT(4);                // B(8) landed; B(9) in flight
    SCHED0;
    SBAR;

    // s=8..13: B-only steady
#define STEP_B(s)                                                \
    COMPUTE(s);                                                  \
    SBAR;                                                        \
    STAGE_B((s) + 2);                                            \
    VMCNT(4);                                                    \
    SCHED0;                                                      \
    SBAR

    STEP_B(8);
    STEP_B(9);
    STEP_B(10);
    STEP_B(11);
    STEP_B(12);
    STEP_B(13);

    COMPUTE(14);
    SBAR;
    VMCNT(0);
    SCHED0;
    SBAR;

    COMPUTE(15);
    EPILOG(1);
    __syncthreads();         // all LDS reads done before sscore aliases buf0

    // ---- cross-lane (16 g-cols) then cross-wave (4 wc) score reduction ----
#pragma unroll
    for (int m = 0; m < 2; ++m)
#pragma unroll
        for (int r = 0; r < 4; ++r) {
            float v = pscore[m][r];
            v += __shfl_xor(v, 1);
            v += __shfl_xor(v, 2);
            v += __shfl_xor(v, 4);
            v += __shfl_xor(v, 8);
            if (lrow == 0)
                sscore[wc * 64 + wr * 32 + m * 16 + lq * 4 + r] = v;
        }
    __syncthreads();

    // ---- w_t = exp(s_t) (no max-sub: |s| <= Sum|w_out| ~ 15, exact shift) ----
    if (tid < 64)
        wlds[tid] = __expf(sscore[0 * 64 + tid] + sscore[1 * 64 + tid] +
                           sscore[2 * 64 + tid] + sscore[3 * 64 + tid]);
    __syncthreads();

    // ---- psum (wave 0) ----
    if (wid == 0) {
        float v = wlds[lane];
        v += __shfl_xor(v, 1);
        v += __shfl_xor(v, 2);
        v += __shfl_xor(v, 4);
        v += __shfl_xor(v, 8);
        v += __shfl_xor(v, 16);
        v += __shfl_xor(v, 32);
        if (lane == 0) psum[b * 32 + chnk] = v;
    }

    // ---- PV tail from LDS: partial[h] = sum_t w_t * key_bf16[t][h] ----
    // key tile is ALREADY in Abase (bf16, padded rows) — no global reads.
    {
        const int h = tid;
        const char* ap = Abase + h * 2;
        float a0 = 0.f;
#pragma unroll 16
        for (int t = 0; t < 64; ++t) {
            unsigned int u = *reinterpret_cast<const unsigned short*>(ap + t * 1040);
            a0 = fmaf(wlds[t], __uint_as_float(u << 16), a0);
        }
        partial[((size_t)(b * 32 + chnk)) * H_N + h] = a0;
    }

#undef LOAD_A
#undef WRITE_A
#undef STAGE_B
#undef COMPUTE
#undef EPILOG
#undef STEP_MID
#undef STEP_B
}

// ---------------------------------------------------------------------------
// K4: out[b][h] = (sum_c partial[b][c][h]) / (sum_c psum[b][c])
// ---------------------------------------------------------------------------
__global__ void k_out(const float* __restrict__ partial, const float* __restrict__ psum,
                      float* __restrict__ out) {
    int idx = blockIdx.x * 256 + threadIdx.x;   // 65536 outputs
    int b = idx >> 9, h = idx & 511;
    float s = 0.f, d = 0.f;
#pragma unroll
    for (int c = 0; c < 32; ++c) {
        s += partial[((size_t)(b * 32 + c)) * H_N + h];
        d += psum[b * 32 + c];
    }
    out[idx] = s / d;
}

extern "C" void kernel_launch(void* const* d_in, const int* in_sizes, int n_in,
                              void* d_out, int out_size, void* d_ws, size_t ws_size,
                              hipStream_t stream) {
    const float* query = (const float*)d_in[0];
    const float* key   = (const float*)d_in[1];
    const float* w1    = (const float*)d_in[2];
    const float* w2    = (const float*)d_in[3];
    const float* w_out = (const float*)d_in[4];
    float* out = (float*)d_out;

    char* ws = (char*)d_ws;
    unsigned short* w2sw = (unsigned short*)(ws);            // 512 KB
    float* qh      = (float*)(ws + 524288);                  // 256 KB
    float* partial = (float*)(ws + 1048576);                 // 8 MB (128*32*512*4)
    float* psum    = (float*)(ws + 9437184);                 // 16 KB

    hipLaunchKernelGGL(k_w2prep, dim3(128),     dim3(256), 0, stream, w2, w2sw);
    hipLaunchKernelGGL(k_qh,     dim3(128),     dim3(512), 0, stream, query, w1, qh);
    hipLaunchKernelGGL(k_scores, dim3(32, 128), dim3(512), 0, stream,
                       key, w2sw, qh, w_out, partial, psum);
    hipLaunchKernelGGL(k_out,    dim3(256),     dim3(256), 0, stream, partial, psum, out);
}